// Round 6
// baseline (39.905 us; speedup 1.0000x reference)
//
#include <hip/hip_runtime.h>
#include <hip/hip_bf16.h>

#define N_NODES 8192
#define E_EDGES 262144
#define DIM 128
#define CAP 128                 // colbuf stride; degree ~ Poisson(32), max << 128
#define LIN_BLOCKS 512          // 16 rows each -> 2 blocks/CU during linear phase
#define SCAT_BLOCKS 768
#define SCAT_THREADS (SCAT_BLOCKS * 256)

// Fused kernel: blocks [0, LIN_BLOCKS) -> linear (h = x @ W^T + b), h stored bf16
//               blocks [LIN_BLOCKS, LIN_BLOCKS+SCAT_BLOCKS) -> edge scatter
__global__ __launch_bounds__(256) void fused_scatter_linear(
        const int* __restrict__ row, const int* __restrict__ col,
        int* __restrict__ cursor, int* __restrict__ colbuf,
        const float* __restrict__ x, const float* __restrict__ W,
        const float* __restrict__ b, __hip_bfloat16* __restrict__ h) {
    __shared__ float xsT[32][20];    // [k_local][row_local], padded
    __shared__ float wsT[32][132];   // [k_local][o], padded
    const int bx  = blockIdx.x;
    const int tid = threadIdx.x;

    if (bx >= LIN_BLOCKS) {
        // ---- scatter path: grid-stride over E edges (~1.33 edges/thread) ----
        int t = (bx - LIN_BLOCKS) * 256 + tid;
        for (int e = t; e < E_EDGES; e += SCAT_THREADS) {
            int r = row[e];
            int slot = atomicAdd(&cursor[r], 1);   // final value == degree (dups counted)
            if (slot < CAP) colbuf[(r << 7) + slot] = col[e];
        }
        return;
    }

    // ---- linear path: 512 blocks, 16 rows each, 2x4 micro-tile ----
    const int r0 = bx * 16;
    const int tx = tid & 31;   // col group: cols tx*4 .. tx*4+3
    const int ty = tid >> 5;   // row group: rows ty*2 .. ty*2+1

    float acc[2][4];
#pragma unroll
    for (int i = 0; i < 2; ++i)
#pragma unroll
        for (int j = 0; j < 4; ++j) acc[i][j] = 0.0f;

    for (int kc = 0; kc < DIM; kc += 32) {
        {
            int kl = tid & 31;
            int rl = tid >> 5;  // 0..7
            xsT[kl][rl]     = x[(size_t)(r0 + rl) * DIM + kc + kl];
            xsT[kl][rl + 8] = x[(size_t)(r0 + rl + 8) * DIM + kc + kl];
        }
        {
            int o  = tid >> 1;            // 0..127
            int kb = (tid & 1) * 16;      // 0 or 16
#pragma unroll
            for (int j = 0; j < 4; ++j) {
                float4 w4 = *(const float4*)&W[(size_t)o * DIM + kc + kb + 4 * j];
                wsT[kb + 4 * j + 0][o] = w4.x;
                wsT[kb + 4 * j + 1][o] = w4.y;
                wsT[kb + 4 * j + 2][o] = w4.z;
                wsT[kb + 4 * j + 3][o] = w4.w;
            }
        }
        __syncthreads();
#pragma unroll
        for (int k = 0; k < 32; ++k) {
            float a0 = xsT[k][ty * 2];
            float a1 = xsT[k][ty * 2 + 1];
            float4 b4 = *(const float4*)&wsT[k][tx * 4];
            float bb[4] = {b4.x, b4.y, b4.z, b4.w};
#pragma unroll
            for (int j = 0; j < 4; ++j) {
                acc[0][j] += a0 * bb[j];
                acc[1][j] += a1 * bb[j];
            }
        }
        __syncthreads();
    }

    float4 bias = *(const float4*)&b[tx * 4];
#pragma unroll
    for (int i = 0; i < 2; ++i) {
        int r = r0 + ty * 2 + i;
        ushort4 o4;
        o4.x = __hip_bfloat16_raw(__float2bfloat16(acc[i][0] + bias.x)).x;
        o4.y = __hip_bfloat16_raw(__float2bfloat16(acc[i][1] + bias.y)).x;
        o4.z = __hip_bfloat16_raw(__float2bfloat16(acc[i][2] + bias.z)).x;
        o4.w = __hip_bfloat16_raw(__float2bfloat16(acc[i][3] + bias.w)).x;
        *(ushort4*)&h[((size_t)r << 7) + tx * 4] = o4;
    }
}

// out[r] = relu( sum_{unique c in adj(r)} rsqrt(deg[r])*rsqrt(deg[c]) * h[c] )
// 2048 blocks x 256 threads: 2 teams of 128, 2 sequential rows per team
__global__ __launch_bounds__(256) void aggregate_kernel(
        const int* __restrict__ deg, const int* __restrict__ colbuf,
        const __hip_bfloat16* __restrict__ h, float* __restrict__ out) {
    __shared__ unsigned int bitmap[2][N_NODES / 32];  // 2 x 1KB
    __shared__ int   klist[2][CAP];
    __shared__ float nlist[2][CAP];
    const int bx   = blockIdx.x;
    const int tid  = threadIdx.x;
    const int team = tid >> 7;     // 0 or 1
    const int lane = tid & 127;

#pragma unroll 1
    for (int rr = 0; rr < 2; ++rr) {
        const int r = (bx << 2) + (team << 1) + rr;
        bitmap[team][lane] = 0u;
        bitmap[team][lane + 128] = 0u;
        __syncthreads();
        const int dr  = deg[r];
        const int cnt = min(dr, CAP);
        const float dinv_r = (dr > 0) ? rsqrtf((float)dr) : 0.0f;
        if (lane < cnt) {
            int c = colbuf[(r << 7) + lane];
            unsigned int bit = 1u << (c & 31);
            unsigned int old = atomicOr(&bitmap[team][c >> 5], bit);
            int dc = deg[c];                   // 32KB array -> L1-resident
            float nv = 0.0f;
            if (!(old & bit) && dc > 0) nv = dinv_r * rsqrtf((float)dc);
            klist[team][lane] = c;             // uniform load; duplicate weight = 0
            nlist[team][lane] = nv;
        }
        __syncthreads();
        float acc = 0.0f;
        int i = 0;
        for (; i + 8 <= cnt; i += 8) {
            float partial = 0.0f;
#pragma unroll
            for (int j = 0; j < 8; ++j) {
                int   c = klist[team][i + j];
                float n = nlist[team][i + j];
                partial += n * __bfloat162float(h[((size_t)c << 7) + lane]);
            }
            acc += partial;
        }
        for (; i < cnt; ++i)
            acc += nlist[team][i] * __bfloat162float(h[((size_t)klist[team][i] << 7) + lane]);
        out[((size_t)r << 7) + lane] = fmaxf(acc, 0.0f);
        __syncthreads();           // protect klist/nlist/bitmap before next row
    }
}

extern "C" void kernel_launch(void* const* d_in, const int* in_sizes, int n_in,
                              void* d_out, int out_size, void* d_ws, size_t ws_size,
                              hipStream_t stream) {
    const float* x  = (const float*)d_in[0];
    const int*   ei = (const int*)d_in[1];
    const float* W  = (const float*)d_in[2];
    const float* b  = (const float*)d_in[3];
    float* out = (float*)d_out;

    char* ws = (char*)d_ws;
    __hip_bfloat16* h = (__hip_bfloat16*)ws;                      // 2 MB
    int*   colbuf = (int*)(ws + (size_t)N_NODES * DIM * 2);       // 4 MB
    int*   cursor = colbuf + (size_t)N_NODES * CAP;               // 32 KB

    const int* row = ei;
    const int* col = ei + E_EDGES;

    hipMemsetAsync(cursor, 0, N_NODES * sizeof(int), stream);
    fused_scatter_linear<<<LIN_BLOCKS + SCAT_BLOCKS, 256, 0, stream>>>(
        row, col, cursor, colbuf, x, W, b, h);
    aggregate_kernel<<<N_NODES / 4, 256, 0, stream>>>(cursor, colbuf, h, out);
}

// Round 7
// 35.618 us; speedup vs baseline: 1.1204x; 1.1204x over previous
//
#include <hip/hip_runtime.h>
#include <hip/hip_bf16.h>

#define N_NODES 8192
#define E_EDGES 262144
#define DIM 128
#define CAP 128                 // colbuf stride; degree ~ Poisson(32), max << 128
#define LIN_BLOCKS 512          // 16 rows each
#define SCAT_BLOCKS 768
#define SCAT_THREADS (SCAT_BLOCKS * 256)

// Fused kernel: blocks [0, LIN_BLOCKS) -> linear (h = x @ W^T + b), h stored bf16
//               blocks [LIN_BLOCKS, ...) -> edge scatter into ushort bucket table
__global__ __launch_bounds__(256) void fused_scatter_linear(
        const int* __restrict__ row, const int* __restrict__ col,
        int* __restrict__ cursor, unsigned short* __restrict__ colbuf,
        const float* __restrict__ x, const float* __restrict__ W,
        const float* __restrict__ b, __hip_bfloat16* __restrict__ h) {
    __shared__ float xsT[32][20];    // [k_local][row_local], padded
    __shared__ float wsT[32][132];   // [k_local][o], padded
    const int bx  = blockIdx.x;
    const int tid = threadIdx.x;

    if (bx >= LIN_BLOCKS) {
        // ---- scatter path: grid-stride over E edges (~1.33 edges/thread) ----
        int t = (bx - LIN_BLOCKS) * 256 + tid;
        for (int e = t; e < E_EDGES; e += SCAT_THREADS) {
            int r = row[e];
            int slot = atomicAdd(&cursor[r], 1);   // final value == degree (dups counted)
            if (slot < CAP) colbuf[(r << 7) + slot] = (unsigned short)col[e];
        }
        return;
    }

    // ---- linear path: 512 blocks, 16 rows each, 2x4 micro-tile ----
    const int r0 = bx * 16;
    const int tx = tid & 31;   // col group: cols tx*4 .. tx*4+3
    const int ty = tid >> 5;   // row group: rows ty*2 .. ty*2+1

    float acc[2][4];
#pragma unroll
    for (int i = 0; i < 2; ++i)
#pragma unroll
        for (int j = 0; j < 4; ++j) acc[i][j] = 0.0f;

    for (int kc = 0; kc < DIM; kc += 32) {
        {
            int kl = tid & 31;
            int rl = tid >> 5;  // 0..7
            xsT[kl][rl]     = x[(size_t)(r0 + rl) * DIM + kc + kl];
            xsT[kl][rl + 8] = x[(size_t)(r0 + rl + 8) * DIM + kc + kl];
        }
        {
            int o  = tid >> 1;            // 0..127
            int kb = (tid & 1) * 16;      // 0 or 16
#pragma unroll
            for (int j = 0; j < 4; ++j) {
                float4 w4 = *(const float4*)&W[(size_t)o * DIM + kc + kb + 4 * j];
                wsT[kb + 4 * j + 0][o] = w4.x;
                wsT[kb + 4 * j + 1][o] = w4.y;
                wsT[kb + 4 * j + 2][o] = w4.z;
                wsT[kb + 4 * j + 3][o] = w4.w;
            }
        }
        __syncthreads();
#pragma unroll
        for (int k = 0; k < 32; ++k) {
            float a0 = xsT[k][ty * 2];
            float a1 = xsT[k][ty * 2 + 1];
            float4 b4 = *(const float4*)&wsT[k][tx * 4];
            float bb[4] = {b4.x, b4.y, b4.z, b4.w};
#pragma unroll
            for (int j = 0; j < 4; ++j) {
                acc[0][j] += a0 * bb[j];
                acc[1][j] += a1 * bb[j];
            }
        }
        __syncthreads();
    }

    float4 bias = *(const float4*)&b[tx * 4];
#pragma unroll
    for (int i = 0; i < 2; ++i) {
        int r = r0 + ty * 2 + i;
        ushort4 o4;
        o4.x = __hip_bfloat16_raw(__float2bfloat16(acc[i][0] + bias.x)).x;
        o4.y = __hip_bfloat16_raw(__float2bfloat16(acc[i][1] + bias.y)).x;
        o4.z = __hip_bfloat16_raw(__float2bfloat16(acc[i][2] + bias.z)).x;
        o4.w = __hip_bfloat16_raw(__float2bfloat16(acc[i][3] + bias.w)).x;
        *(ushort4*)&h[((size_t)r << 7) + tx * 4] = o4;
    }
}

// out[r] = relu( sum_{unique c in adj(r)} rsqrt(deg[r])*rsqrt(deg[c]) * h[c] )
// 2048 blocks x 256 threads: 4 teams of 64 lanes, 1 row per team.
// Each lane owns dims (2*lane, 2*lane+1): ushort2 gathers, float2 store.
__global__ __launch_bounds__(256) void aggregate_kernel(
        const int* __restrict__ deg, const unsigned short* __restrict__ colbuf,
        const __hip_bfloat16* __restrict__ h, float* __restrict__ out) {
    __shared__ unsigned int bitmap[4][N_NODES / 32];  // 4 x 1KB
    __shared__ int   klist[4][CAP];
    __shared__ float nlist[4][CAP];
    const int bx   = blockIdx.x;
    const int tid  = threadIdx.x;
    const int team = tid >> 6;     // 0..3
    const int lane = tid & 63;
    const int r    = (bx << 2) + team;

#pragma unroll
    for (int j = 0; j < 4; ++j) bitmap[team][lane * 4 + j] = 0u;
    __syncthreads();

    const int dr  = deg[r];
    const int cnt = min(dr, CAP);
    const float dinv_r = (dr > 0) ? rsqrtf((float)dr) : 0.0f;

#pragma unroll
    for (int half = 0; half < 2; ++half) {
        int s = lane + 64 * half;
        if (s < cnt) {
            int c = colbuf[(r << 7) + s];
            unsigned int bit = 1u << (c & 31);
            unsigned int old = atomicOr(&bitmap[team][c >> 5], bit);
            int dc = deg[c];                   // 32KB array -> cache-resident
            float nv = 0.0f;
            if (!(old & bit) && dc > 0) nv = dinv_r * rsqrtf((float)dc);
            klist[team][s] = c;                // uniform later load; duplicate weight = 0
            nlist[team][s] = nv;
        }
    }
    __syncthreads();

    float acc0 = 0.0f, acc1 = 0.0f;
    int i = 0;
    for (; i + 8 <= cnt; i += 8) {
#pragma unroll
        for (int j = 0; j < 8; ++j) {
            int   c = klist[team][i + j];
            float n = nlist[team][i + j];
            ushort2 hv = *(const ushort2*)&h[((size_t)c << 7) + lane * 2];
            acc0 += n * __bfloat162float(*(const __hip_bfloat16*)&hv.x);
            acc1 += n * __bfloat162float(*(const __hip_bfloat16*)&hv.y);
        }
    }
    for (; i < cnt; ++i) {
        int   c = klist[team][i];
        float n = nlist[team][i];
        ushort2 hv = *(const ushort2*)&h[((size_t)c << 7) + lane * 2];
        acc0 += n * __bfloat162float(*(const __hip_bfloat16*)&hv.x);
        acc1 += n * __bfloat162float(*(const __hip_bfloat16*)&hv.y);
    }

    float2 o2 = make_float2(fmaxf(acc0, 0.0f), fmaxf(acc1, 0.0f));
    *(float2*)&out[((size_t)r << 7) + lane * 2] = o2;
}

extern "C" void kernel_launch(void* const* d_in, const int* in_sizes, int n_in,
                              void* d_out, int out_size, void* d_ws, size_t ws_size,
                              hipStream_t stream) {
    const float* x  = (const float*)d_in[0];
    const int*   ei = (const int*)d_in[1];
    const float* W  = (const float*)d_in[2];
    const float* b  = (const float*)d_in[3];
    float* out = (float*)d_out;

    char* ws = (char*)d_ws;
    __hip_bfloat16* h = (__hip_bfloat16*)ws;                              // 2 MB
    unsigned short* colbuf = (unsigned short*)(ws + (size_t)N_NODES * DIM * 2);  // 2 MB
    int* cursor = (int*)(ws + (size_t)N_NODES * DIM * 2 + (size_t)N_NODES * CAP * 2); // 32 KB

    const int* row = ei;
    const int* col = ei + E_EDGES;

    hipMemsetAsync(cursor, 0, N_NODES * sizeof(int), stream);
    fused_scatter_linear<<<LIN_BLOCKS + SCAT_BLOCKS, 256, 0, stream>>>(
        row, col, cursor, colbuf, x, W, b, h);
    aggregate_kernel<<<N_NODES / 4, 256, 0, stream>>>(cursor, colbuf, h, out);
}